// Round 7
// baseline (339.028 us; speedup 1.0000x reference)
//
#include <hip/hip_runtime.h>
#include <hip/hip_bf16.h>

#define NB 4
#define NI 40000
#define DI 512
#define NH 128

typedef __attribute__((ext_vector_type(8))) short bf16x8;
typedef __attribute__((ext_vector_type(4))) float f32x4;

__device__ __forceinline__ ushort f2b(float f) {
    union { float f; unsigned u; } x; x.f = f;
    unsigned r = x.u + 0x7FFFu + ((x.u >> 16) & 1u);
    return (ushort)(r >> 16);
}
__device__ __forceinline__ float tanh_fast(float x) {
    x = fminf(15.f, fmaxf(-15.f, x));
    float e = __expf(2.f * x);
    return (e - 1.f) / (e + 1.f);
}

// ---------------- weight transpose + bf16 convert ----------------
__global__ void k_wt(const float* __restrict__ w1, const float* __restrict__ w2,
                     ushort* __restrict__ w1t, ushort* __restrict__ w2t) {
    int idx = blockIdx.x * 256 + threadIdx.x;
    if (idx < 65536) {
        int j = idx >> 9, i = idx & 511;
        w1t[idx] = f2b(w1[i * 128 + j]);
    } else if (idx < 81920) {
        int r = idx - 65536;
        int j = r >> 7, k = r & 127;
        w2t[r] = f2b(w2[k * 128 + j]);
    }
}

// ---------------- argmax stage 1 ----------------
__global__ void k_am1(const float* __restrict__ c, float* __restrict__ pv, int* __restrict__ pi) {
    int blk = blockIdx.x;
    int bo = blk >> 4, ch = blk & 15;
    int b = bo >> 1, o = bo & 1;
    __shared__ float rv[256];
    __shared__ int   ri[256];
    int tid = threadIdx.x;
    float bv = -3.402823466e38f; int bi = 0x7fffffff;
    for (int n = ch * 2500 + tid; n < (ch + 1) * 2500; n += 256) {
        float v = c[((size_t)b * NI + n) * 2 + o];
        if (v > bv || (v == bv && n < bi)) { bv = v; bi = n; }
    }
    rv[tid] = bv; ri[tid] = bi;
    __syncthreads();
    for (int s = 128; s > 0; s >>= 1) {
        if (tid < s) {
            if (rv[tid + s] > rv[tid] || (rv[tid + s] == rv[tid] && ri[tid + s] < ri[tid])) {
                rv[tid] = rv[tid + s]; ri[tid] = ri[tid + s];
            }
        }
        __syncthreads();
    }
    if (tid == 0) { pv[blk] = rv[0]; pi[blk] = ri[0]; }
}

// ---------------- q_max MLP (argmax stage-2 fused) ----------------
__global__ void k_qmax(const float* __restrict__ feats,
                       const float* __restrict__ pv, const int* __restrict__ pi,
                       const float* __restrict__ w1, const float* __restrict__ b1,
                       const float* __restrict__ w2, const float* __restrict__ b2,
                       float* __restrict__ qmax) {
    int bo = blockIdx.x;
    int b = bo >> 1;
    __shared__ float xs[DI];
    __shared__ float hs[NH];
    __shared__ int s_idx;
    int tid = threadIdx.x;               // 512
    if (tid == 0) {
        float bv = -3.402823466e38f; int bi = 0x7fffffff;
        for (int ch = 0; ch < 16; ++ch) {
            float v = pv[bo * 16 + ch]; int idx = pi[bo * 16 + ch];
            if (v > bv || (v == bv && idx < bi)) { bv = v; bi = idx; }
        }
        s_idx = bi;
    }
    __syncthreads();
    const float* x = feats + ((size_t)b * NI + s_idx) * DI;
    if (tid < DI) xs[tid] = x[tid];
    __syncthreads();
    int j = tid >> 2, part = tid & 3;
    float p = 0.f;
    for (int i = part * 128; i < part * 128 + 128; ++i)
        p += xs[i] * w1[i * NH + j];
    p += __shfl_xor(p, 1); p += __shfl_xor(p, 2);
    if (part == 0) { float h = p + b1[j]; hs[j] = h > 0.f ? h : 0.f; }
    __syncthreads();
    p = 0.f;
    for (int i = part * 32; i < part * 32 + 32; ++i)
        p += hs[i] * w2[i * NH + j];
    p += __shfl_xor(p, 1); p += __shfl_xor(p, 2);
    if (part == 0) qmax[bo * NH + j] = tanhf(p + b2[j]);
}

// ---------------- fused main: wave-autonomous MLP + e + fused U ----------------
// 2500 blocks x 256 threads. Each wave owns 16 instances end-to-end:
//   L1: A-frags straight from global (f32, 16 rows x 128B contiguous / instr),
//       B-frags from L2-resident w1t. No staging, no barriers.
//   H transpose via private per-wave 4KB LDS slice (same-wave dep only).
//   L2 MFMA with w2t from L2. Softmax dot via 16-lane shfl reduce.
//   U: re-read own 16 rows (L3-hot), accumulate e*x in regs.
// One __syncthreads at the end for the block-level u reduction.
__global__ __launch_bounds__(256, 3)
void k_mlp(const float* __restrict__ feats,
           const ushort* __restrict__ w1t, const ushort* __restrict__ w2t,
           const float* __restrict__ b1, const float* __restrict__ b2,
           const float* __restrict__ qmax,
           float* __restrict__ ews, float* __restrict__ zp, float* __restrict__ Up) {
    __shared__ ushort h_lds[4][2048];      // 4KB per wave, XOR-swizzled
    __shared__ float  u_lds[4][2][DI];     // 16KB, final reduce only

    const int tid  = threadIdx.x;
    const int wv   = tid >> 6;
    const int lane = tid & 63;
    const int lr   = lane & 15;
    const int lkg  = lane >> 4;
    const int lk   = lkg * 8;
    const int l4   = lkg * 4;

    const int bk  = blockIdx.x;
    const int b   = bk / 625;
    const int blk = bk - b * 625;
    const int n0  = blk * 64 + wv * 16;          // this wave's first instance
    const float* fb = feats + ((size_t)b * NI + n0) * DI;

    // per-lane constants (col = n*16+lr for col-tile n)
    float qm0[8], qm1[8], b1v[8], b2v[8];
#pragma unroll
    for (int n = 0; n < 8; ++n) {
        int col = n * 16 + lr;
        qm0[n] = qmax[b * 256 + col];
        qm1[n] = qmax[b * 256 + NH + col];
        b1v[n] = b1[col];
        b2v[n] = b2[col];
    }

    // ---- layer 1: X[16,512] @ W1[512,128] ----
    f32x4 acc[8] = {};
    {
        const float* arow = fb + (size_t)lr * DI + lk;
#pragma unroll
        for (int kc = 0; kc < 16; ++kc) {
            float4 xa = *(const float4*)(arow + kc * 32);
            float4 xb = *(const float4*)(arow + kc * 32 + 4);
            unsigned p0, p1, p2, p3;
            asm("v_cvt_pk_bf16_f32 %0, %1, %2" : "=v"(p0) : "v"(xa.x), "v"(xa.y));
            asm("v_cvt_pk_bf16_f32 %0, %1, %2" : "=v"(p1) : "v"(xa.z), "v"(xa.w));
            asm("v_cvt_pk_bf16_f32 %0, %1, %2" : "=v"(p2) : "v"(xb.x), "v"(xb.y));
            asm("v_cvt_pk_bf16_f32 %0, %1, %2" : "=v"(p3) : "v"(xb.z), "v"(xb.w));
            union { unsigned u[4]; bf16x8 v; } A;
            A.u[0] = p0; A.u[1] = p1; A.u[2] = p2; A.u[3] = p3;
#pragma unroll
            for (int n = 0; n < 8; ++n) {
                bf16x8 w = *(const bf16x8*)&w1t[(size_t)(n * 16 + lr) * DI + kc * 32 + lk];
                acc[n] = __builtin_amdgcn_mfma_f32_16x16x32_bf16(A.v, w, acc[n], 0, 0, 0);
            }
        }
    }

    // ---- epilogue 1: bias+relu -> per-wave h_lds (bf16, XOR-swizzled) ----
    {
        char* hb = (char*)&h_lds[wv][0];
#pragma unroll
        for (int n = 0; n < 8; ++n) {
            int col2 = (n * 16 + lr) * 2;
#pragma unroll
            for (int r = 0; r < 4; ++r) {
                int row = l4 + r;
                float v = acc[n][r] + b1v[n];
                *(ushort*)(hb + row * 256 + (col2 ^ ((row & 7) << 4))) =
                    f2b(v > 0.f ? v : 0.f);
            }
        }
    }

    // ---- layer 2: H[16,128] @ W2[128,128] (same-wave LDS dep; no barrier) ----
    f32x4 q[8] = {};
    {
        const char* hr = (const char*)&h_lds[wv][0] + lr * 256;
        const int rsw = (lr & 7) << 4;
#pragma unroll
        for (int kc = 0; kc < 4; ++kc) {
            bf16x8 a = *(const bf16x8*)(hr + ((kc * 64 + lk * 2) ^ rsw));
#pragma unroll
            for (int n = 0; n < 8; ++n) {
                bf16x8 w = *(const bf16x8*)&w2t[(size_t)(n * 16 + lr) * NH + kc * 32 + lk];
                q[n] = __builtin_amdgcn_mfma_f32_16x16x32_bf16(a, w, q[n], 0, 0, 0);
            }
        }
    }

    // ---- epilogue 2: tanh + dot(qmax); 16-lane reduce -> row sums ----
    float e0[4], e1[4];
    {
        float p0[4] = {}, p1[4] = {};
#pragma unroll
        for (int n = 0; n < 8; ++n)
#pragma unroll
            for (int r = 0; r < 4; ++r) {
                float qq = tanh_fast(q[n][r] + b2v[n]);
                p0[r] += qq * qm0[n];
                p1[r] += qq * qm1[n];
            }
#pragma unroll
        for (int r = 0; r < 4; ++r) {
            p0[r] += __shfl_xor(p0[r], 1); p1[r] += __shfl_xor(p1[r], 1);
            p0[r] += __shfl_xor(p0[r], 2); p1[r] += __shfl_xor(p1[r], 2);
            p0[r] += __shfl_xor(p0[r], 4); p1[r] += __shfl_xor(p1[r], 4);
            p0[r] += __shfl_xor(p0[r], 8); p1[r] += __shfl_xor(p1[r], 8);
            e0[r] = __expf(p0[r] * 0.005f);    // /sqrt(40000)
            e1[r] = __expf(p1[r] * 0.005f);
        }
    }

    // ---- e writes + z partial (rows l4+r live replicated across 16-lane group) ----
    if (lr == 0) {
        size_t base = ((size_t)b * NI + n0 + l4) * 2;
#pragma unroll
        for (int r = 0; r < 4; ++r) {
            ews[base + r * 2]     = e0[r];
            ews[base + r * 2 + 1] = e1[r];
        }
    }
    {
        float z0 = e0[0] + e0[1] + e0[2] + e0[3];
        float z1 = e1[0] + e1[1] + e1[2] + e1[3];
        z0 += __shfl_xor(z0, 16); z1 += __shfl_xor(z1, 16);
        z0 += __shfl_xor(z0, 32); z1 += __shfl_xor(z1, 32);
        if (lane == 0) {
            int t = blk * 4 + wv;
            zp[(b * 2500 + t) * 2]     = z0;
            zp[(b * 2500 + t) * 2 + 1] = z1;
        }
    }

    // ---- fused U: re-read own 16 rows (L3-hot), accumulate e*x ----
    float4 u00 = {0,0,0,0}, u01 = {0,0,0,0}, u10 = {0,0,0,0}, u11 = {0,0,0,0};
#pragma unroll
    for (int r = 0; r < 16; ++r) {
        float4 xA = *(const float4*)(fb + (size_t)r * DI + lane * 4);
        float4 xB = *(const float4*)(fb + (size_t)r * DI + 256 + lane * 4);
        float er0 = __shfl(e0[r & 3], (r >> 2) * 16 + (lane & 15));
        float er1 = __shfl(e1[r & 3], (r >> 2) * 16 + (lane & 15));
        u00.x += er0 * xA.x; u00.y += er0 * xA.y; u00.z += er0 * xA.z; u00.w += er0 * xA.w;
        u01.x += er0 * xB.x; u01.y += er0 * xB.y; u01.z += er0 * xB.z; u01.w += er0 * xB.w;
        u10.x += er1 * xA.x; u10.y += er1 * xA.y; u10.z += er1 * xA.z; u10.w += er1 * xA.w;
        u11.x += er1 * xB.x; u11.y += er1 * xB.y; u11.z += er1 * xB.z; u11.w += er1 * xB.w;
    }

    // ---- block u reduce (single barrier) ----
    *(float4*)&u_lds[wv][0][lane * 4]       = u00;
    *(float4*)&u_lds[wv][0][256 + lane * 4] = u01;
    *(float4*)&u_lds[wv][1][lane * 4]       = u10;
    *(float4*)&u_lds[wv][1][256 + lane * 4] = u11;
    __syncthreads();
    {
        int o = tid >> 7, d4 = tid & 127;
        float4 s = {0,0,0,0};
#pragma unroll
        for (int w = 0; w < 4; ++w) {
            float4 v = *(const float4*)&u_lds[w][o][d4 * 4];
            s.x += v.x; s.y += v.y; s.z += v.z; s.w += v.w;
        }
        *(float4*)&Up[(((size_t)(b * 625 + blk)) * 2 + o) * DI + d4 * 4] = s;
    }
}

// ---------------- Z reduce (2500 partials per (b,o)) ----------------
__global__ void k_zred(const float* __restrict__ zp, float* __restrict__ Zt) {
    int bo = blockIdx.x; int b = bo >> 1, o = bo & 1;
    __shared__ float red[256];
    int tid = threadIdx.x;
    float z = 0.f;
    for (int t = tid; t < 2500; t += 256) z += zp[(b * 2500 + t) * 2 + o];
    red[tid] = z; __syncthreads();
    for (int s = 128; s > 0; s >>= 1) {
        if (tid < s) red[tid] += red[tid + s];
        __syncthreads();
    }
    if (tid == 0) Zt[bo] = red[0];
}

// ---------------- A output ----------------
__global__ void k_A(const float* __restrict__ ews, const float* __restrict__ Zt,
                    float* __restrict__ outA) {
    int idx = blockIdx.x * 256 + threadIdx.x;
    int b = idx / (NI * 2);
    int o = idx & 1;
    outA[idx] = ews[idx] / Zt[b * 2 + o];
}

// ---------------- B reduce: 64 blocks = (bo, 64-d chunk) ----------------
__global__ void k_B(const float* __restrict__ Up, const float* __restrict__ Zt,
                    float* __restrict__ outB) {
    __shared__ float r_lds[4][64];
    const int bo = blockIdx.x >> 3, ch = blockIdx.x & 7;
    const int b = bo >> 1, o = bo & 1;
    const int tid = threadIdx.x;          // 256
    const int pg = tid >> 6, dl = tid & 63;
    const int d = ch * 64 + dl;
    float u = 0.f;
    for (int j = pg; j < 625; j += 4)
        u += Up[((size_t)(b * 625 + j) * 2 + o) * DI + d];
    r_lds[pg][dl] = u;
    __syncthreads();
    if (tid < 64)
        outB[bo * DI + d] = (r_lds[0][dl] + r_lds[1][dl] + r_lds[2][dl] + r_lds[3][dl]) / Zt[bo];
}

// ---------------- C output ----------------
__global__ void k_C(const float* __restrict__ outB, const float* __restrict__ fcc_w,
                    const float* __restrict__ fcc_b, float* __restrict__ outC) {
    int bo = blockIdx.x; int b = bo >> 1, o = bo & 1;
    __shared__ float red[256];
    int tid = threadIdx.x;
    float acc = 0.f;
    for (int idx = tid; idx < 2 * DI; idx += 256) {
        int i = idx >> 9, d = idx & 511;
        acc += outB[(b * 2 + i) * DI + d] * fcc_w[o * (2 * DI) + i * DI + d];
    }
    red[tid] = acc; __syncthreads();
    for (int s = 128; s > 0; s >>= 1) {
        if (tid < s) red[tid] += red[tid + s];
        __syncthreads();
    }
    if (tid == 0) outC[bo] = red[0] + fcc_b[o];
}

extern "C" void kernel_launch(void* const* d_in, const int* in_sizes, int n_in,
                              void* d_out, int out_size, void* d_ws, size_t ws_size,
                              hipStream_t stream) {
    const float* feats = (const float*)d_in[0];
    const float* c     = (const float*)d_in[1];
    const float* q_w1  = (const float*)d_in[2];
    const float* q_b1  = (const float*)d_in[3];
    const float* q_w2  = (const float*)d_in[4];
    const float* q_b2  = (const float*)d_in[5];
    const float* fcc_w = (const float*)d_in[6];
    const float* fcc_b = (const float*)d_in[7];
    float* out = (float*)d_out;

    // workspace layout (bytes)
    char* w = (char*)d_ws;
    ushort* w1t  = (ushort*)(w);                 // 131072
    ushort* w2t  = (ushort*)(w + 131072);        //  32768 -> 163840
    float* qmaxb = (float*)(w + 163840);         //   4096 -> 167936
    float* Zt    = (float*)(w + 167936);         //     32 -> 167968
    float* pv    = (float*)(w + 167968);         //    512 -> 168480
    int*   pi    = (int*)(w + 168480);           //    512 -> 168992
    float* ews   = (float*)(w + 169024);         // 1280000 -> 1449024
    float* zp    = (float*)(w + 1449024);        //  80000 -> 1529024
    float* Up    = (float*)(w + 1529088);        // 10240000 -> 11769088

    float* outC = out;
    float* outA = out + 8;
    float* outB = out + 8 + NB * NI * 2;

    k_wt<<<320, 256, 0, stream>>>(q_w1, q_w2, w1t, w2t);
    k_am1<<<128, 256, 0, stream>>>(c, pv, pi);
    k_qmax<<<8, 512, 0, stream>>>(feats, pv, pi, q_w1, q_b1, q_w2, q_b2, qmaxb);
    k_mlp<<<2500, 256, 0, stream>>>(feats, w1t, w2t, q_b1, q_b2, qmaxb, ews, zp, Up);
    k_zred<<<8, 256, 0, stream>>>(zp, Zt);
    k_A<<<NB * NI * 2 / 256, 256, 0, stream>>>(ews, Zt, outA);
    k_B<<<64, 256, 0, stream>>>(Up, Zt, outB);
    k_C<<<8, 256, 0, stream>>>(outB, fcc_w, fcc_b, outC);
}